// Round 5
// baseline (484.045 us; speedup 1.0000x reference)
//
#include <hip/hip_runtime.h>
#include <hip/hip_bf16.h>

#define H   128
#define ND  64
#define TILE_R 64

typedef __bf16  bf16x8 __attribute__((ext_vector_type(8)));
typedef float   f32x4  __attribute__((ext_vector_type(4)));

__device__ __forceinline__ unsigned short f2bf(float f) {
  return __bfloat16_as_ushort(__float2bfloat16(f));
}
__device__ __forceinline__ float bf2f(unsigned short u) {
  return __uint_as_float(((unsigned int)u) << 16);
}

// ---------------- CSR build (scan-free) ----------------

__global__ __launch_bounds__(256) void count_deg_k(const int* __restrict__ dst,
                                                   int* __restrict__ cnt, int E) {
  int e = blockIdx.x * 256 + threadIdx.x;
  if (e < E) atomicAdd(&cnt[dst[e]], 1);
}

// Segment placement: wave-level scan + one atomic per wave. Segment order in
// ssrc is arbitrary — aggregation only needs off[node] / cnt[node].
__global__ __launch_bounds__(256) void alloc_k(const int* __restrict__ cnt,
                                               int* __restrict__ off,
                                               int* __restrict__ cur,
                                               int* __restrict__ ctr, int n) {
  int i = blockIdx.x * 256 + threadIdx.x;
  int lane = threadIdx.x & 63;
  int c = (i < n) ? cnt[i] : 0;
  int x = c;
#pragma unroll
  for (int o = 1; o < 64; o <<= 1) {
    int t = __shfl_up(x, o, 64);
    if (lane >= o) x += t;
  }
  int total = __shfl(x, 63, 64);
  int base = 0;
  if (lane == 63) base = atomicAdd(ctr, total);
  base = __shfl(base, 63, 64);
  int p = base + x - c;            // exclusive within wave
  if (i < n) { off[i] = p; cur[i] = p; }
}

__global__ __launch_bounds__(256) void scatter_k(const int* __restrict__ src,
                                                 const int* __restrict__ dst,
                                                 int* __restrict__ cur,
                                                 int* __restrict__ ssrc, int E) {
  int e = blockIdx.x * 256 + threadIdx.x;
  if (e < E) {
    int d = dst[e];
    int p = atomicAdd(&cur[d], 1);
    ssrc[p] = src[e];
  }
}

// ---------------- weight fragment prep (Wg x3 + Wp in one dispatch) --------
// chunk c = combo*64 + lane; o[j] = W[kb+j][nc] with nc=(combo/KS)*16+(lane&15),
// kb=(combo%KS)*32+(lane>>4)*8.  Same bytes serve as A-frags of W^T.

__global__ __launch_bounds__(256) void prep_all_k(const float* __restrict__ Wg,
                                                  const float* __restrict__ Wp,
                                                  unsigned short* __restrict__ wfrag,
                                                  unsigned short* __restrict__ wpfrag) {
  __shared__ float sW[H * H];                     // 64 KB
  if (blockIdx.x < 3) {
    const float* W = Wg + (size_t)blockIdx.x * H * H;
    for (int i = threadIdx.x; i < H * H; i += 256) sW[i] = W[i];
    __syncthreads();
    unsigned short* out = wfrag + (size_t)blockIdx.x * 2048 * 8;
    for (int c = threadIdx.x; c < 2048; c += 256) {
      int lane = c & 63, combo = c >> 6;
      int it = combo >> 2, ks = combo & 3;
      int nc = it * 16 + (lane & 15);
      int kb = ks * 32 + (lane >> 4) * 8;
      unsigned short* o = out + (size_t)c * 8;
#pragma unroll
      for (int j = 0; j < 8; ++j) o[j] = f2bf(sW[(kb + j) * H + nc]);
    }
  } else {
    for (int i = threadIdx.x; i < ND * H; i += 256) sW[i] = Wp[i];
    __syncthreads();
    for (int c = threadIdx.x; c < 1024; c += 256) {
      int lane = c & 63, combo = c >> 6;
      int it = combo >> 1, ks = combo & 1;
      int nc = it * 16 + (lane & 15);
      int kb = ks * 32 + (lane >> 4) * 8;
      unsigned short* o = wpfrag + (size_t)c * 8;
#pragma unroll
      for (int j = 0; j < 8; ++j) o[j] = f2bf(sW[(kb + j) * H + nc]);
    }
  }
}

// ---------------- node projection: hb = bf16(x @ Wp + bp) -------------------
// Operand-swapped MFMA: D[feature=quad*4+r + it*16][node=lane&15].
// B-frags read straight from fp32 x (distinct addrs per lane, no broadcast).

__global__ __launch_bounds__(256, 4) void proj_mfma_k(const float* __restrict__ x,
                                                      const unsigned short* __restrict__ wpfrag,
                                                      const float* __restrict__ bp,
                                                      unsigned short* __restrict__ hout,
                                                      int n) {
  __shared__ unsigned short sB[1024 * 8];         // 16 KB (Wp^T A-frags)
  uint4* sB4 = (uint4*)sB;
  const uint4* wsrc = (const uint4*)wpfrag;
  for (int i = threadIdx.x; i < 1024; i += 256) sB4[i] = wsrc[i];
  __syncthreads();

  int wave = threadIdx.x >> 6, lane = threadIdx.x & 63;
  int quad = lane >> 4, n16 = lane & 15;
  int node = blockIdx.x * 64 + wave * 16 + n16;

  union { unsigned short s[8]; uint4 u; bf16x8 b; } bm[2];
  if (node < n) {
    const float* xr = x + (size_t)node * ND;
#pragma unroll
    for (int ks = 0; ks < 2; ++ks) {
      const float* pk = xr + ks * 32 + quad * 8;
      float4 A0 = *(const float4*)pk;
      float4 A1 = *(const float4*)(pk + 4);
      bm[ks].s[0] = f2bf(A0.x); bm[ks].s[1] = f2bf(A0.y);
      bm[ks].s[2] = f2bf(A0.z); bm[ks].s[3] = f2bf(A0.w);
      bm[ks].s[4] = f2bf(A1.x); bm[ks].s[5] = f2bf(A1.y);
      bm[ks].s[6] = f2bf(A1.z); bm[ks].s[7] = f2bf(A1.w);
    }
  } else {
    bm[0].u = make_uint4(0, 0, 0, 0);
    bm[1].u = make_uint4(0, 0, 0, 0);
  }

  f32x4 acc[8] = {};
#pragma unroll
  for (int it = 0; it < 8; ++it) {
#pragma unroll
    for (int ks = 0; ks < 2; ++ks) {
      union { uint4 u; bf16x8 b; } aw;
      aw.u = sB4[(it * 2 + ks) * 64 + lane];
      acc[it] = __builtin_amdgcn_mfma_f32_16x16x32_bf16(aw.b, bm[ks].b, acc[it], 0, 0, 0);
    }
  }

  unsigned short* rout = hout + (size_t)node * H;   // hout padded to N_pad rows
#pragma unroll
  for (int it = 0; it < 8; ++it) {
    int f0 = it * 16 + quad * 4;
    float4 bv = *(const float4*)(bp + f0);
    ushort4 o = make_ushort4(f2bf(acc[it][0] + bv.x), f2bf(acc[it][1] + bv.y),
                             f2bf(acc[it][2] + bv.z), f2bf(acc[it][3] + bv.w));
    *(ushort4*)(rout + f0) = o;
  }
}

// ---------------- fused layer: hout = relu(hin + mean-agg(hin) @ Wg + bg) ----
// Phase 1: half-wave gather into LDS msg tile (padded row 136 halves).
// Phase 2: operand-swapped MFMA from LDS + vectorized epilogue.
// Ping-pong hin/hout avoids the inter-block gather/update race.

__global__ __launch_bounds__(256, 3) void fused_layer_k(
    const unsigned short* __restrict__ hin,
    unsigned short* __restrict__ hout,
    const int* __restrict__ off, const int* __restrict__ cnt,
    const int* __restrict__ ssrc,
    const unsigned short* __restrict__ wfrag,
    const float* __restrict__ bg, int n) {
  __shared__ unsigned short sB[2048 * 8];         // 32 KB (Wg^T A-frags)
  __shared__ unsigned short sM[64 * 136];         // 17 KB msg tile, padded
  uint4* sB4 = (uint4*)sB;
  const uint4* wsrc = (const uint4*)wfrag;
  for (int i = threadIdx.x; i < 2048; i += 256) sB4[i] = wsrc[i];

  int tile0 = blockIdx.x * 64;
  int hw = threadIdx.x >> 5, l = threadIdx.x & 31;
#pragma unroll 1
  for (int u = 0; u < 8; ++u) {
    int ln = hw * 8 + u;
    int node = tile0 + ln;
    float4 acc = {0.f, 0.f, 0.f, 0.f};
    int deg = 0;
    if (node < n) {
      int beg = off[node];
      deg = cnt[node];
      int e = beg, end = beg + deg;
      for (; e + 4 <= end; e += 4) {
        int s0 = ssrc[e], s1 = ssrc[e + 1], s2 = ssrc[e + 2], s3 = ssrc[e + 3];
        ushort4 v0 = ((const ushort4*)(hin + (size_t)s0 * H))[l];
        ushort4 v1 = ((const ushort4*)(hin + (size_t)s1 * H))[l];
        ushort4 v2 = ((const ushort4*)(hin + (size_t)s2 * H))[l];
        ushort4 v3 = ((const ushort4*)(hin + (size_t)s3 * H))[l];
        acc.x += bf2f(v0.x) + bf2f(v1.x) + bf2f(v2.x) + bf2f(v3.x);
        acc.y += bf2f(v0.y) + bf2f(v1.y) + bf2f(v2.y) + bf2f(v3.y);
        acc.z += bf2f(v0.z) + bf2f(v1.z) + bf2f(v2.z) + bf2f(v3.z);
        acc.w += bf2f(v0.w) + bf2f(v1.w) + bf2f(v2.w) + bf2f(v3.w);
      }
      for (; e < end; ++e) {
        int s0 = ssrc[e];
        ushort4 v0 = ((const ushort4*)(hin + (size_t)s0 * H))[l];
        acc.x += bf2f(v0.x); acc.y += bf2f(v0.y);
        acc.z += bf2f(v0.z); acc.w += bf2f(v0.w);
      }
    }
    float inv = (deg > 0) ? 1.0f / (float)deg : 0.f;
    ushort4 o = make_ushort4(f2bf(acc.x * inv), f2bf(acc.y * inv),
                             f2bf(acc.z * inv), f2bf(acc.w * inv));
    *(ushort4*)(&sM[ln * 136 + l * 4]) = o;
  }
  __syncthreads();

  int wave = threadIdx.x >> 6, lane = threadIdx.x & 63;
  int quad = lane >> 4, n16 = lane & 15;
  int node = tile0 + wave * 16 + n16;

  union { uint4 u; bf16x8 b; } bm[4];
  const unsigned short* mrow = &sM[(wave * 16 + n16) * 136];
#pragma unroll
  for (int ks = 0; ks < 4; ++ks)
    bm[ks].u = *(const uint4*)(mrow + ks * 32 + quad * 8);

  f32x4 acc[8] = {};
#pragma unroll
  for (int it = 0; it < 8; ++it) {
#pragma unroll
    for (int ks = 0; ks < 4; ++ks) {
      union { uint4 u; bf16x8 b; } aw;
      aw.u = sB4[(it * 4 + ks) * 64 + lane];
      acc[it] = __builtin_amdgcn_mfma_f32_16x16x32_bf16(aw.b, bm[ks].b, acc[it], 0, 0, 0);
    }
  }

  const unsigned short* rin = hin + (size_t)node * H;   // padded rows: in-bounds
  unsigned short* rout = hout + (size_t)node * H;
#pragma unroll
  for (int it = 0; it < 8; ++it) {
    int f0 = it * 16 + quad * 4;
    float4 bv = *(const float4*)(bg + f0);
    ushort4 old = *(const ushort4*)(rin + f0);
    float v0 = bf2f(old.x) + acc[it][0] + bv.x; v0 = v0 > 0.f ? v0 : 0.f;
    float v1 = bf2f(old.y) + acc[it][1] + bv.y; v1 = v1 > 0.f ? v1 : 0.f;
    float v2 = bf2f(old.z) + acc[it][2] + bv.z; v2 = v2 > 0.f ? v2 : 0.f;
    float v3 = bf2f(old.w) + acc[it][3] + bv.w; v3 = v3 > 0.f ? v3 : 0.f;
    *(ushort4*)(rout + f0) = make_ushort4(f2bf(v0), f2bf(v1), f2bf(v2), f2bf(v3));
  }
}

// ---------------- global mean pool (bf16 input, fp32 accumulate) ------------

__global__ __launch_bounds__(256) void reduce_mean_bf_k(const unsigned short* __restrict__ hb,
                                                        float* __restrict__ gsum, int n) {
  int c  = threadIdx.x & 31;        // 4-col chunk
  int rg = threadIdx.x >> 5;        // 0..7
  float4 acc = {0.f, 0.f, 0.f, 0.f};
  for (int row = blockIdx.x * 8 + rg; row < n; row += gridDim.x * 8) {
    ushort4 v = ((const ushort4*)(hb + (size_t)row * H))[c];
    acc.x += bf2f(v.x); acc.y += bf2f(v.y);
    acc.z += bf2f(v.z); acc.w += bf2f(v.w);
  }
  __shared__ float4 s[256];
  s[threadIdx.x] = acc;
  __syncthreads();
  if (threadIdx.x < 32) {
    float4 t = s[c];
#pragma unroll
    for (int k = 1; k < 8; ++k) {
      float4 q = s[k * 32 + c];
      t.x += q.x; t.y += q.y; t.z += q.z; t.w += q.w;
    }
    atomicAdd(&gsum[c * 4 + 0], t.x);
    atomicAdd(&gsum[c * 4 + 1], t.y);
    atomicAdd(&gsum[c * 4 + 2], t.z);
    atomicAdd(&gsum[c * 4 + 3], t.w);
  }
}

// ---------------- MLP head ----------------

__global__ __launch_bounds__(256) void mlp_k(const float* __restrict__ gsum,
                                             const float* __restrict__ W1,
                                             const float* __restrict__ b1,
                                             const float* __restrict__ W2,
                                             const float* __restrict__ b2,
                                             float* __restrict__ out, float invN) {
  __shared__ float g[H];
  __shared__ float hid[H];
  int tid = threadIdx.x;
  if (tid < H) g[tid] = gsum[tid] * invN;
  __syncthreads();
  if (tid < H) {
    float acc = b1[tid];
    for (int k = 0; k < H; ++k) acc += g[k] * W1[k * H + tid];
    hid[tid] = acc > 0.f ? acc : 0.f;
  }
  __syncthreads();
  float acc = b2[tid];
  for (int k = 0; k < H; ++k) acc += hid[k] * W2[k * 256 + tid];
  out[tid] = acc;
}

// ---------------- launcher ----------------

extern "C" void kernel_launch(void* const* d_in, const int* in_sizes, int n_in,
                              void* d_out, int out_size, void* d_ws, size_t ws_size,
                              hipStream_t stream) {
  const float* x  = (const float*)d_in[0];
  const int*   src = (const int*)d_in[1];
  const int*   dst = (const int*)d_in[2];
  const float* Wp = (const float*)d_in[3];
  const float* bp = (const float*)d_in[4];
  const float* Wg = (const float*)d_in[5];
  const float* bg = (const float*)d_in[6];
  const float* W1 = (const float*)d_in[7];
  const float* b1 = (const float*)d_in[8];
  const float* W2 = (const float*)d_in[9];
  const float* b2 = (const float*)d_in[10];
  float* out = (float*)d_out;

  const int N = in_sizes[0] / ND;   // 50000
  const int E = in_sizes[1];        // 800000
  const int N_pad = ((N + TILE_R - 1) / TILE_R) * TILE_R;  // 50048
  const size_t NH = (size_t)N_pad * H;

  char* p = (char*)d_ws;
  unsigned short* hb0   = (unsigned short*)p; p += NH * sizeof(unsigned short);
  unsigned short* hb1   = (unsigned short*)p; p += NH * sizeof(unsigned short);
  unsigned short* wfrag = (unsigned short*)p; p += 3 * 2048 * 8 * sizeof(unsigned short);
  unsigned short* wpfrag= (unsigned short*)p; p += 1024 * 8 * sizeof(unsigned short);
  int*   off  = (int*)p;   p += (size_t)N * sizeof(int);
  int*   cur  = (int*)p;   p += (size_t)N * sizeof(int);
  int*   ssrc = (int*)p;   p += (size_t)E * sizeof(int);
  // zero-init region (single memset): cnt | ctr | gsum
  int*   cnt  = (int*)p;   p += (size_t)N * sizeof(int);
  int*   ctr  = (int*)p;   p += sizeof(int);
  float* gsum = (float*)p; p += H * sizeof(float);

  const int ntiles = N_pad / TILE_R;    // 782

  hipMemsetAsync(cnt, 0, ((size_t)N + 1 + H) * sizeof(int), stream);

  // CSR build (scan-free)
  count_deg_k<<<(E + 255) / 256, 256, 0, stream>>>(dst, cnt, E);
  alloc_k<<<(N + 255) / 256, 256, 0, stream>>>(cnt, off, cur, ctr, N);
  scatter_k<<<(E + 255) / 256, 256, 0, stream>>>(src, dst, cur, ssrc, E);

  // weight prep (Wg x3 + Wp)
  prep_all_k<<<4, 256, 0, stream>>>(Wg, Wp, wfrag, wpfrag);

  // node projection -> hb0
  proj_mfma_k<<<ntiles, 256, 0, stream>>>(x, wpfrag, bp, hb0, N);

  // 3 fused GNN layers (ping-pong hb0/hb1)
  fused_layer_k<<<ntiles, 256, 0, stream>>>(hb0, hb1, off, cnt, ssrc,
                                            wfrag + 0 * 2048 * 8, bg + 0 * H, N);
  fused_layer_k<<<ntiles, 256, 0, stream>>>(hb1, hb0, off, cnt, ssrc,
                                            wfrag + 1 * 2048 * 8, bg + 1 * H, N);
  fused_layer_k<<<ntiles, 256, 0, stream>>>(hb0, hb1, off, cnt, ssrc,
                                            wfrag + 2 * 2048 * 8, bg + 2 * H, N);

  // mean pool + MLP head
  reduce_mean_bf_k<<<256, 256, 0, stream>>>(hb1, gsum, N);
  mlp_k<<<1, 256, 0, stream>>>(gsum, W1, b1, W2, b2, out, 1.0f / (float)N);
}

// Round 6
// 350.037 us; speedup vs baseline: 1.3828x; 1.3828x over previous
//
#include <hip/hip_runtime.h>
#include <hip/hip_bf16.h>

#define H   128
#define ND  64
#define TILE_R 64

typedef __bf16  bf16x8 __attribute__((ext_vector_type(8)));
typedef float   f32x4  __attribute__((ext_vector_type(4)));

__device__ __forceinline__ unsigned short f2bf(float f) {
  return __bfloat16_as_ushort(__float2bfloat16(f));
}
__device__ __forceinline__ float bf2f(unsigned short u) {
  return __uint_as_float(((unsigned int)u) << 16);
}
__device__ __forceinline__ unsigned int pack2(float a, float b) {
  return (unsigned int)f2bf(a) | ((unsigned int)f2bf(b) << 16);
}

// ---------------- CSR build (scan-free) ----------------

__global__ __launch_bounds__(256) void count_deg_k(const int* __restrict__ dst,
                                                   int* __restrict__ cnt, int E) {
  int e = blockIdx.x * 256 + threadIdx.x;
  if (e < E) atomicAdd(&cnt[dst[e]], 1);
}

__global__ __launch_bounds__(256) void alloc_k(const int* __restrict__ cnt,
                                               int* __restrict__ off,
                                               int* __restrict__ cur,
                                               int* __restrict__ ctr, int n) {
  int i = blockIdx.x * 256 + threadIdx.x;
  int lane = threadIdx.x & 63;
  int c = (i < n) ? cnt[i] : 0;
  int x = c;
#pragma unroll
  for (int o = 1; o < 64; o <<= 1) {
    int t = __shfl_up(x, o, 64);
    if (lane >= o) x += t;
  }
  int total = __shfl(x, 63, 64);
  int base = 0;
  if (lane == 63) base = atomicAdd(ctr, total);
  base = __shfl(base, 63, 64);
  int p = base + x - c;
  if (i < n) { off[i] = p; cur[i] = p; }
}

// ssrc stored as ushort (N < 65536) — halves scatter payload + gather reads.
__global__ __launch_bounds__(256) void scatter_k(const int* __restrict__ src,
                                                 const int* __restrict__ dst,
                                                 int* __restrict__ cur,
                                                 unsigned short* __restrict__ ssrc, int E) {
  int e = blockIdx.x * 256 + threadIdx.x;
  if (e < E) {
    int d = dst[e];
    int p = atomicAdd(&cur[d], 1);
    ssrc[p] = (unsigned short)src[e];
  }
}

// ---------------- weight fragment prep ----------------
// o[j] = W[kb+j][nc]; nc=(combo/KS)*16+(lane&15), kb=(combo%KS)*32+(lane>>4)*8.
// These bytes serve as A-frags of W^T for the swapped-operand MFMA.

__global__ __launch_bounds__(256) void prep_all_k(const float* __restrict__ Wg,
                                                  const float* __restrict__ Wp,
                                                  unsigned short* __restrict__ wfrag,
                                                  unsigned short* __restrict__ wpfrag) {
  __shared__ float sW[H * H];
  if (blockIdx.x < 3) {
    const float* W = Wg + (size_t)blockIdx.x * H * H;
    for (int i = threadIdx.x; i < H * H; i += 256) sW[i] = W[i];
    __syncthreads();
    unsigned short* out = wfrag + (size_t)blockIdx.x * 2048 * 8;
    for (int c = threadIdx.x; c < 2048; c += 256) {
      int lane = c & 63, combo = c >> 6;
      int it = combo >> 2, ks = combo & 3;
      int nc = it * 16 + (lane & 15);
      int kb = ks * 32 + (lane >> 4) * 8;
      unsigned short* o = out + (size_t)c * 8;
#pragma unroll
      for (int j = 0; j < 8; ++j) o[j] = f2bf(sW[(kb + j) * H + nc]);
    }
  } else {
    for (int i = threadIdx.x; i < ND * H; i += 256) sW[i] = Wp[i];
    __syncthreads();
    for (int c = threadIdx.x; c < 1024; c += 256) {
      int lane = c & 63, combo = c >> 6;
      int it = combo >> 1, ks = combo & 1;
      int nc = it * 16 + (lane & 15);
      int kb = ks * 32 + (lane >> 4) * 8;
      unsigned short* o = wpfrag + (size_t)c * 8;
#pragma unroll
      for (int j = 0; j < 8; ++j) o[j] = f2bf(sW[(kb + j) * H + nc]);
    }
  }
}

// ---------------- node projection: hb = bf16(x @ Wp + bp) -------------------

__global__ __launch_bounds__(256, 4) void proj_mfma_k(const float* __restrict__ x,
                                                      const unsigned short* __restrict__ wpfrag,
                                                      const float* __restrict__ bp,
                                                      unsigned short* __restrict__ hout,
                                                      int n) {
  __shared__ unsigned short sB[1024 * 8];         // 16 KB
  uint4* sB4 = (uint4*)sB;
  const uint4* wsrc = (const uint4*)wpfrag;
  for (int i = threadIdx.x; i < 1024; i += 256) sB4[i] = wsrc[i];
  __syncthreads();

  int wave = threadIdx.x >> 6, lane = threadIdx.x & 63;
  int quad = lane >> 4, n16 = lane & 15;
  int node = blockIdx.x * 64 + wave * 16 + n16;

  union { unsigned short s[8]; uint4 u; bf16x8 b; } bm[2];
  if (node < n) {
    const float* xr = x + (size_t)node * ND;
#pragma unroll
    for (int ks = 0; ks < 2; ++ks) {
      const float* pk = xr + ks * 32 + quad * 8;
      float4 A0 = *(const float4*)pk;
      float4 A1 = *(const float4*)(pk + 4);
      bm[ks].s[0] = f2bf(A0.x); bm[ks].s[1] = f2bf(A0.y);
      bm[ks].s[2] = f2bf(A0.z); bm[ks].s[3] = f2bf(A0.w);
      bm[ks].s[4] = f2bf(A1.x); bm[ks].s[5] = f2bf(A1.y);
      bm[ks].s[6] = f2bf(A1.z); bm[ks].s[7] = f2bf(A1.w);
    }
  } else {
    bm[0].u = make_uint4(0, 0, 0, 0);
    bm[1].u = make_uint4(0, 0, 0, 0);
  }

  f32x4 acc[8] = {};
#pragma unroll
  for (int it = 0; it < 8; ++it) {
#pragma unroll
    for (int ks = 0; ks < 2; ++ks) {
      union { uint4 u; bf16x8 b; } aw;
      aw.u = sB4[(it * 2 + ks) * 64 + lane];
      acc[it] = __builtin_amdgcn_mfma_f32_16x16x32_bf16(aw.b, bm[ks].b, acc[it], 0, 0, 0);
    }
  }

  unsigned short* rout = hout + (size_t)node * H;
#pragma unroll
  for (int it = 0; it < 8; ++it) {
    int f0 = it * 16 + quad * 4;
    float4 bv = *(const float4*)(bp + f0);
    ushort4 o = make_ushort4(f2bf(acc[it][0] + bv.x), f2bf(acc[it][1] + bv.y),
                             f2bf(acc[it][2] + bv.z), f2bf(acc[it][3] + bv.w));
    *(ushort4*)(rout + f0) = o;
  }
}

// ---------------- aggregation: msgb = bf16(mean-agg(hin)) -------------------
// Half-wave (32 lanes) per node. Edge ids loaded coalesced (32 at a time,
// lane-parallel) then shfl-broadcast. Two edges per step: lanes 0-15 edge j,
// lanes 16-31 edge j+1, each lane reads 16 B (16 lanes x uint4 = full row).
// Cross-phase combine via shfl_xor(16); lanes 0-15 write 16 B of msgb.

__global__ __launch_bounds__(256) void aggregate_bf_k(
    const unsigned short* __restrict__ hin,
    const int* __restrict__ off, const int* __restrict__ cnt,
    const unsigned short* __restrict__ ssrc,
    unsigned short* __restrict__ msgb, int n) {
  int node = blockIdx.x * 8 + (threadIdx.x >> 5);
  if (node >= n) return;
  int l = threadIdx.x & 31;
  int l16 = l & 15, phase = l >> 4;
  int beg = off[node], deg = cnt[node];
  float acc[8] = {};
  for (int base = 0; base < deg; base += 32) {
    int m = deg - base; if (m > 32) m = 32;
    int idx = base + l;
    int eid = (int)ssrc[beg + (idx < deg ? idx : deg - 1)];
#pragma unroll 4
    for (int j = 0; j < m; j += 2) {
      int jj = j + phase;
      int s = __shfl(eid, jj, 32);
      if (jj < m) {
        uint4 v = *(const uint4*)(hin + (size_t)s * H + l16 * 8);
        acc[0] += __uint_as_float(v.x << 16);
        acc[1] += __uint_as_float(v.x & 0xffff0000u);
        acc[2] += __uint_as_float(v.y << 16);
        acc[3] += __uint_as_float(v.y & 0xffff0000u);
        acc[4] += __uint_as_float(v.z << 16);
        acc[5] += __uint_as_float(v.z & 0xffff0000u);
        acc[6] += __uint_as_float(v.w << 16);
        acc[7] += __uint_as_float(v.w & 0xffff0000u);
      }
    }
  }
#pragma unroll
  for (int k = 0; k < 8; ++k) acc[k] += __shfl_xor(acc[k], 16, 32);
  if (phase == 0) {
    float inv = (deg > 0) ? 1.0f / (float)deg : 0.f;
    uint4 o;
    o.x = pack2(acc[0] * inv, acc[1] * inv);
    o.y = pack2(acc[2] * inv, acc[3] * inv);
    o.z = pack2(acc[4] * inv, acc[5] * inv);
    o.w = pack2(acc[6] * inv, acc[7] * inv);
    *(uint4*)(msgb + (size_t)node * H + l16 * 8) = o;
  }
}

// ---------------- update: hout = relu(hin + msgb @ Wg + bg) -----------------
// Swapped-operand MFMA: A = Wg^T frags (LDS), B = msgb frags (global, distinct
// 16-B per lane). D[feature = it*16+quad*4+r][node = lane&15].

__global__ __launch_bounds__(256, 4) void update_mfma_k(
    const unsigned short* __restrict__ hin,
    unsigned short* __restrict__ hout,
    const unsigned short* __restrict__ msgb,
    const unsigned short* __restrict__ wfrag,
    const float* __restrict__ bg, int n) {
  __shared__ unsigned short sB[2048 * 8];         // 32 KB
  uint4* sB4 = (uint4*)sB;
  const uint4* wsrc = (const uint4*)wfrag;
  for (int i = threadIdx.x; i < 2048; i += 256) sB4[i] = wsrc[i];
  __syncthreads();

  int wave = threadIdx.x >> 6, lane = threadIdx.x & 63;
  int quad = lane >> 4, n16 = lane & 15;
  int node = blockIdx.x * 64 + wave * 16 + n16;

  union { uint4 u; bf16x8 b; } bm[4];
  const unsigned short* mrow = msgb + (size_t)node * H;
#pragma unroll
  for (int ks = 0; ks < 4; ++ks)
    bm[ks].u = *(const uint4*)(mrow + ks * 32 + quad * 8);

  f32x4 acc[8] = {};
#pragma unroll
  for (int it = 0; it < 8; ++it) {
#pragma unroll
    for (int ks = 0; ks < 4; ++ks) {
      union { uint4 u; bf16x8 b; } aw;
      aw.u = sB4[(it * 4 + ks) * 64 + lane];
      acc[it] = __builtin_amdgcn_mfma_f32_16x16x32_bf16(aw.b, bm[ks].b, acc[it], 0, 0, 0);
    }
  }

  const unsigned short* rin = hin + (size_t)node * H;
  unsigned short* rout = hout + (size_t)node * H;
#pragma unroll
  for (int it = 0; it < 8; ++it) {
    int f0 = it * 16 + quad * 4;
    float4 bv = *(const float4*)(bg + f0);
    ushort4 old = *(const ushort4*)(rin + f0);
    float v0 = bf2f(old.x) + acc[it][0] + bv.x; v0 = v0 > 0.f ? v0 : 0.f;
    float v1 = bf2f(old.y) + acc[it][1] + bv.y; v1 = v1 > 0.f ? v1 : 0.f;
    float v2 = bf2f(old.z) + acc[it][2] + bv.z; v2 = v2 > 0.f ? v2 : 0.f;
    float v3 = bf2f(old.w) + acc[it][3] + bv.w; v3 = v3 > 0.f ? v3 : 0.f;
    *(ushort4*)(rout + f0) = make_ushort4(f2bf(v0), f2bf(v1), f2bf(v2), f2bf(v3));
  }
}

// ---------------- global mean pool (bf16 input, fp32 accumulate) ------------

__global__ __launch_bounds__(256) void reduce_mean_bf_k(const unsigned short* __restrict__ hb,
                                                        float* __restrict__ gsum, int n) {
  int c  = threadIdx.x & 31;
  int rg = threadIdx.x >> 5;
  float4 acc = {0.f, 0.f, 0.f, 0.f};
  for (int row = blockIdx.x * 8 + rg; row < n; row += gridDim.x * 8) {
    ushort4 v = ((const ushort4*)(hb + (size_t)row * H))[c];
    acc.x += bf2f(v.x); acc.y += bf2f(v.y);
    acc.z += bf2f(v.z); acc.w += bf2f(v.w);
  }
  __shared__ float4 s[256];
  s[threadIdx.x] = acc;
  __syncthreads();
  if (threadIdx.x < 32) {
    float4 t = s[c];
#pragma unroll
    for (int k = 1; k < 8; ++k) {
      float4 q = s[k * 32 + c];
      t.x += q.x; t.y += q.y; t.z += q.z; t.w += q.w;
    }
    atomicAdd(&gsum[c * 4 + 0], t.x);
    atomicAdd(&gsum[c * 4 + 1], t.y);
    atomicAdd(&gsum[c * 4 + 2], t.z);
    atomicAdd(&gsum[c * 4 + 3], t.w);
  }
}

// ---------------- MLP head ----------------

__global__ __launch_bounds__(256) void mlp_k(const float* __restrict__ gsum,
                                             const float* __restrict__ W1,
                                             const float* __restrict__ b1,
                                             const float* __restrict__ W2,
                                             const float* __restrict__ b2,
                                             float* __restrict__ out, float invN) {
  __shared__ float g[H];
  __shared__ float hid[H];
  int tid = threadIdx.x;
  if (tid < H) g[tid] = gsum[tid] * invN;
  __syncthreads();
  if (tid < H) {
    float acc = b1[tid];
    for (int k = 0; k < H; ++k) acc += g[k] * W1[k * H + tid];
    hid[tid] = acc > 0.f ? acc : 0.f;
  }
  __syncthreads();
  float acc = b2[tid];
  for (int k = 0; k < H; ++k) acc += hid[k] * W2[k * 256 + tid];
  out[tid] = acc;
}

// ---------------- launcher ----------------

extern "C" void kernel_launch(void* const* d_in, const int* in_sizes, int n_in,
                              void* d_out, int out_size, void* d_ws, size_t ws_size,
                              hipStream_t stream) {
  const float* x  = (const float*)d_in[0];
  const int*   src = (const int*)d_in[1];
  const int*   dst = (const int*)d_in[2];
  const float* Wp = (const float*)d_in[3];
  const float* bp = (const float*)d_in[4];
  const float* Wg = (const float*)d_in[5];
  const float* bg = (const float*)d_in[6];
  const float* W1 = (const float*)d_in[7];
  const float* b1 = (const float*)d_in[8];
  const float* W2 = (const float*)d_in[9];
  const float* b2 = (const float*)d_in[10];
  float* out = (float*)d_out;

  const int N = in_sizes[0] / ND;   // 50000 (< 65536 — ssrc is ushort)
  const int E = in_sizes[1];        // 800000
  const int N_pad = ((N + TILE_R - 1) / TILE_R) * TILE_R;
  const size_t NH = (size_t)N_pad * H;

  char* p = (char*)d_ws;
  unsigned short* hb0   = (unsigned short*)p; p += NH * sizeof(unsigned short);
  unsigned short* hb1   = (unsigned short*)p; p += NH * sizeof(unsigned short);
  unsigned short* msgb  = (unsigned short*)p; p += NH * sizeof(unsigned short);
  unsigned short* wfrag = (unsigned short*)p; p += 3 * 2048 * 8 * sizeof(unsigned short);
  unsigned short* wpfrag= (unsigned short*)p; p += 1024 * 8 * sizeof(unsigned short);
  int*   off  = (int*)p;   p += (size_t)N * sizeof(int);
  int*   cur  = (int*)p;   p += (size_t)N * sizeof(int);
  unsigned short* ssrc = (unsigned short*)p; p += (size_t)E * sizeof(unsigned short);
  p = (char*)(((uintptr_t)p + 3) & ~(uintptr_t)3);
  // zero-init region (single memset): cnt | ctr | gsum
  int*   cnt  = (int*)p;   p += (size_t)N * sizeof(int);
  int*   ctr  = (int*)p;   p += sizeof(int);
  float* gsum = (float*)p; p += H * sizeof(float);

  const int ntiles = N_pad / TILE_R;

  hipMemsetAsync(cnt, 0, ((size_t)N + 1 + H) * sizeof(int), stream);

  // CSR build (scan-free)
  count_deg_k<<<(E + 255) / 256, 256, 0, stream>>>(dst, cnt, E);
  alloc_k<<<(N + 255) / 256, 256, 0, stream>>>(cnt, off, cur, ctr, N);
  scatter_k<<<(E + 255) / 256, 256, 0, stream>>>(src, dst, cur, ssrc, E);

  // weight prep
  prep_all_k<<<4, 256, 0, stream>>>(Wg, Wp, wfrag, wpfrag);

  // node projection -> hb0
  proj_mfma_k<<<ntiles, 256, 0, stream>>>(x, wpfrag, bp, hb0, N);

  // 3 GNN layers (split agg/update, bf16 ping-pong)
  unsigned short* hin = hb0;
  unsigned short* hout = hb1;
  for (int l = 0; l < 3; ++l) {
    aggregate_bf_k<<<(N + 7) / 8, 256, 0, stream>>>(hin, off, cnt, ssrc, msgb, N);
    update_mfma_k<<<ntiles, 256, 0, stream>>>(hin, hout, msgb,
                                              wfrag + (size_t)l * 2048 * 8,
                                              bg + (size_t)l * H, N);
    unsigned short* t = hin; hin = hout; hout = t;
  }

  // mean pool + MLP head (final h is in `hin` after the last swap)
  reduce_mean_bf_k<<<256, 256, 0, stream>>>(hin, gsum, N);
  mlp_k<<<1, 256, 0, stream>>>(gsum, W1, b1, W2, b2, out, 1.0f / (float)N);
}